// Round 4
// baseline (260.394 us; speedup 1.0000x reference)
//
#include <hip/hip_runtime.h>
#include <math.h>

// B=8192 rows, F=3072 features, block=3.
//
// v4b: v4 with the nontemporal-store compile fix (builtin needs a native
// clang vector type, not HIP's float4 struct).
// Theory recap: duration tracks resident-wave count almost linearly
// (occ 74/67/52% -> 88/92/103 us across v1/v2/v3); access pattern and
// per-wave in-flight depth are both non-factors. v3's launch_bounds(256,6)
// needlessly capped 24 waves/CU at 36 VGPRs -> restore (256,8) for the full
// 32 waves/CU. grid=2048, ROWS=4: exactly 8 WGs/CU, single generation.
// Also: FETCH_SIZE (98MB) < logical reads (192MB) -> L3 already serves half
// the reads; x+w+y = 288MB > 256MB L3, so write-once-read-never y thrashes
// x/w. Nontemporal stores keep y out of L3 so x+w (192MB) mostly fits.
#define BATCH 8192
#define FEAT  3072
#define TPB   256
#define ROWS  4
#define NWG   (BATCH / ROWS)   // 2048 = 256 CUs x 8 WGs
#define RS4   (FEAT / 4)       // row stride in float4 units

typedef float floatx4 __attribute__((ext_vector_type(4)));

// Analytic log|det J| for the d=3 Moebius block:
//   T(z) = w + (1-|w|^2)(z+w)/|z+w|^2 is conformal, DT = lambda*(I-2nn^T),
//   lambda = (1-|w|^2)/|z+w|^2 = c. For y = r*T(x/r): |det J| = c^(d-1) = c^2.
//   sum log|det| = 2*ln2 * sum log2(c).

__global__ __launch_bounds__(TPB, 8)   // 36 VGPR measured -> 8 waves/EU fits
void moebius_kernel(const float* __restrict__ x,
                    const float* __restrict__ w,
                    float* __restrict__ out) {
    __shared__ float swred[TPB / 64][ROWS];

    const int tid  = threadIdx.x;
    const int lane = tid & 63;
    const int wave = tid >> 6;
    // Thread owns 12 contiguous floats (4 blocks) per row.
    const size_t base = (size_t)blockIdx.x * ROWS * FEAT + 12 * tid;

    const float4* __restrict__ x4 = (const float4*)(x + base);
    const float4* __restrict__ w4 = (const float4*)(w + base);
    floatx4* __restrict__ y4      = (floatx4*)(out + base);

    // Register double buffer: [2] x {x,w} x 3 float4 = 48 VGPRs (reused).
    float4 bx[2][3], bw[2][3];
    bx[0][0] = x4[0]; bx[0][1] = x4[1]; bx[0][2] = x4[2];
    bw[0][0] = w4[0]; bw[0][1] = w4[1]; bw[0][2] = w4[2];

    #pragma unroll   // full unroll: all [i&1] indices compile-time (no scratch)
    for (int i = 0; i < ROWS; ++i) {
        const int cur = i & 1;
        if (i + 1 < ROWS) {   // prefetch next row BEFORE waiting on this one
            const int nxt = cur ^ 1;
            const int o = (i + 1) * RS4;
            bx[nxt][0] = x4[o + 0]; bx[nxt][1] = x4[o + 1]; bx[nxt][2] = x4[o + 2];
            bw[nxt][0] = w4[o + 0]; bw[nxt][1] = w4[o + 1]; bw[nxt][2] = w4[o + 2];
        }

        const float4 xa = bx[cur][0], xb = bx[cur][1], xc = bx[cur][2];
        const float4 wa = bw[cur][0], wb = bw[cur][1], wc = bw[cur][2];
        const float X[12] = {xa.x, xa.y, xa.z, xa.w, xb.x, xb.y, xb.z, xb.w,
                             xc.x, xc.y, xc.z, xc.w};
        const float W[12] = {wa.x, wa.y, wa.z, wa.w, wb.x, wb.y, wb.z, wb.w,
                             wc.x, wc.y, wc.z, wc.w};
        float Y[12];
        float lsum = 0.0f;   // accumulates log2(c)

        #pragma unroll
        for (int j = 0; j < 4; ++j) {
            const float x0 = X[3 * j], x1 = X[3 * j + 1], x2 = X[3 * j + 2];
            const float w0 = W[3 * j], w1 = W[3 * j + 1], w2 = W[3 * j + 2];

            // fmaxf guard: numerically inert for real inputs but blocks the
            // only inf->NaN path (rsq(0)=inf, 0*inf=NaN).
            const float r2   = fmaxf(x0 * x0 + x1 * x1 + x2 * x2, 1e-30f);
            const float invr = __builtin_amdgcn_rsqf(r2);   // 1/|x|
            const float r    = r2 * invr;                   // |x|

            const float p0 = x0 * invr + w0;
            const float p1 = x1 * invr + w1;
            const float p2 = x2 * invr + w2;

            const float wns  = w0 * w0 + w1 * w1 + w2 * w2;
            const float xwns = fmaxf(p0 * p0 + p1 * p1 + p2 * p2, 1e-30f);
            const float cc   = (1.0f - wns) * __builtin_amdgcn_rcpf(xwns);

            Y[3 * j]     = r * (cc * p0 + w0);
            Y[3 * j + 1] = r * (cc * p1 + w1);
            Y[3 * j + 2] = r * (cc * p2 + w2);

            lsum += __builtin_amdgcn_logf(cc);   // log2(c)
        }

        // Nontemporal: y is write-once-read-never; keep it out of L2/L3 so
        // the x/w streams stay resident in Infinity Cache across iterations.
        {
            floatx4 v0 = {Y[0], Y[1], Y[2],  Y[3]};
            floatx4 v1 = {Y[4], Y[5], Y[6],  Y[7]};
            floatx4 v2 = {Y[8], Y[9], Y[10], Y[11]};
            __builtin_nontemporal_store(v0, &y4[i * RS4 + 0]);
            __builtin_nontemporal_store(v1, &y4[i * RS4 + 1]);
            __builtin_nontemporal_store(v2, &y4[i * RS4 + 2]);
        }

        // Per-row wave reduction (no barrier); cross-wave sum deferred.
        #pragma unroll
        for (int off = 32; off > 0; off >>= 1) {
            lsum += __shfl_down(lsum, off, 64);
        }
        if (lane == 0) swred[wave][i] = lsum;
    }

    __syncthreads();   // single barrier per WG
    if (tid < ROWS) {
        const float tot = (swred[0][tid] + swred[1][tid] +
                           swred[2][tid] + swred[3][tid]) * 1.3862943611f;
        out[(size_t)BATCH * FEAT + (size_t)blockIdx.x * ROWS + tid] = tot;
    }
}

extern "C" void kernel_launch(void* const* d_in, const int* in_sizes, int n_in,
                              void* d_out, int out_size, void* d_ws, size_t ws_size,
                              hipStream_t stream) {
    const float* x = (const float*)d_in[0];
    const float* w = (const float*)d_in[1];
    float* out = (float*)d_out;   // [B*F] y followed by [B] log_det_J

    moebius_kernel<<<NWG, TPB, 0, stream>>>(x, w, out);
}

// Round 5
// 244.311 us; speedup vs baseline: 1.0658x; 1.0658x over previous
//
#include <hip/hip_runtime.h>
#include <math.h>

// B=8192 rows, F=3072 features, block=3. One WG per row (v1 structure — the
// measured best: 88 us, occ 74%; persistence/occupancy experiments all
// regressed).
//
// v5: attack the write-allocate path. Across ALL versions FETCH_SIZE ==
// WRITE_SIZE to within 0.2% (~98 MB each) while logical reads are 192 MB ->
// x/w are L3-resident across bench iterations and the entire HBM fetch is
// read-for-ownership fills for y lines. Fix: nontemporal stores, but (unlike
// v4b, which amplified WRITE 98->123 MB by nt-ing 48B-stride fragments) make
// every store instruction cover whole 64B lines: stage y through LDS, then
// store fully-coalesced float4 runs (1 KB contiguous per wave-instruction).
#define BATCH 8192
#define FEAT  3072
#define TPB   256

typedef float floatx4 __attribute__((ext_vector_type(4)));

// Analytic log|det J| for the d=3 Moebius block:
//   T(z) = w + (1-|w|^2)(z+w)/|z+w|^2 is conformal, DT = lambda*(I-2nn^T),
//   lambda = (1-|w|^2)/|z+w|^2 = c. For y = r*T(x/r): |det J| = c^(d-1) = c^2.
//   sum log|det| = 2*ln2 * sum log2(c).

__global__ __launch_bounds__(TPB, 8)
void moebius_kernel(const float* __restrict__ x,
                    const float* __restrict__ w,
                    float* __restrict__ out) {
    __shared__ __align__(16) float sy[FEAT];   // y staging, 12 KB
    __shared__ float swred[TPB / 64];

    const int row = blockIdx.x;
    const int tid = threadIdx.x;
    const size_t rbase = (size_t)row * FEAT;
    const size_t base  = rbase + 12 * tid;   // 12 contiguous floats per thread

    const float4* __restrict__ x4 = (const float4*)(x + base);
    const float4* __restrict__ w4 = (const float4*)(w + base);

    // Six independent 16B loads, all issued up front (6 KB/wave in flight).
    const float4 xa = x4[0], xb = x4[1], xc = x4[2];
    const float4 wa = w4[0], wb = w4[1], wc = w4[2];

    const float X[12] = {xa.x, xa.y, xa.z, xa.w, xb.x, xb.y, xb.z, xb.w,
                         xc.x, xc.y, xc.z, xc.w};
    const float W[12] = {wa.x, wa.y, wa.z, wa.w, wb.x, wb.y, wb.z, wb.w,
                         wc.x, wc.y, wc.z, wc.w};
    float Y[12];

    float lsum = 0.0f;   // accumulates log2(c)

    #pragma unroll
    for (int j = 0; j < 4; ++j) {
        const float x0 = X[3 * j], x1 = X[3 * j + 1], x2 = X[3 * j + 2];
        const float w0 = W[3 * j], w1 = W[3 * j + 1], w2 = W[3 * j + 2];

        // fmaxf guard: numerically inert for real inputs (P(r2<1e-30)~0) but
        // blocks the only inf->NaN propagation path (rsq(0)=inf, 0*inf=NaN).
        const float r2   = fmaxf(x0 * x0 + x1 * x1 + x2 * x2, 1e-30f);
        const float invr = __builtin_amdgcn_rsqf(r2);   // 1/|x|
        const float r    = r2 * invr;                   // |x|

        const float p0 = x0 * invr + w0;
        const float p1 = x1 * invr + w1;
        const float p2 = x2 * invr + w2;

        const float wns  = w0 * w0 + w1 * w1 + w2 * w2;
        const float xwns = fmaxf(p0 * p0 + p1 * p1 + p2 * p2, 1e-30f);
        const float cc   = (1.0f - wns) * __builtin_amdgcn_rcpf(xwns);  // > 0

        Y[3 * j]     = r * (cc * p0 + w0);
        Y[3 * j + 1] = r * (cc * p1 + w1);
        Y[3 * j + 2] = r * (cc * p2 + w2);

        lsum += __builtin_amdgcn_logf(cc);   // log2(c)
    }

    // Stage y in LDS as three b128 writes at 48B lane stride: per-phase bank
    // coverage is exactly 2-way (free, m136); measured 0 conflicts in v2.
    {
        floatx4* s = (floatx4*)(sy + 12 * tid);
        s[0] = (floatx4){Y[0], Y[1], Y[2],  Y[3]};
        s[1] = (floatx4){Y[4], Y[5], Y[6],  Y[7]};
        s[2] = (floatx4){Y[8], Y[9], Y[10], Y[11]};
    }

    // Row reduction: wave shuffle (64 lanes) then cross-wave LDS.
    #pragma unroll
    for (int off = 32; off > 0; off >>= 1) {
        lsum += __shfl_down(lsum, off, 64);
    }
    const int lane = tid & 63;
    const int wave = tid >> 6;
    if (lane == 0) swred[wave] = lsum;
    __syncthreads();   // y staged + swred visible

    // Fully line-coalesced nontemporal stores: each wave-instruction writes
    // 1 KB contiguous (16 whole 64B lines) -> nt can't fragment lines, and
    // the no-allocate hint skips the RFO fill that is (theory) the entire
    // 98 MB HBM FETCH.
    {
        const floatx4* __restrict__ s4 = (const floatx4*)sy;
        floatx4* __restrict__ y4 = (floatx4*)(out + rbase);
        __builtin_nontemporal_store(s4[tid],       &y4[tid]);
        __builtin_nontemporal_store(s4[tid + 256], &y4[tid + 256]);
        __builtin_nontemporal_store(s4[tid + 512], &y4[tid + 512]);
    }

    if (tid == 0) {
        const float tot = (swred[0] + swred[1] + swred[2] + swred[3]) * 1.3862943611f;
        out[(size_t)BATCH * FEAT + row] = tot;   // 2*ln2 * sum(log2 c)
    }
}

extern "C" void kernel_launch(void* const* d_in, const int* in_sizes, int n_in,
                              void* d_out, int out_size, void* d_ws, size_t ws_size,
                              hipStream_t stream) {
    const float* x = (const float*)d_in[0];
    const float* w = (const float*)d_in[1];
    float* out = (float*)d_out;   // [B*F] y followed by [B] log_det_J

    moebius_kernel<<<BATCH, TPB, 0, stream>>>(x, w, out);
}